// Round 4
// baseline (354.021 us; speedup 1.0000x reference)
//
#include <hip/hip_runtime.h>
#include <math.h>

#define B_ROWS 4096
#define DIM    1024
#define NTOT   8192
#define NCLS   40
#define TILESG 64    // 8192 / 128
#define NBLKG  2080  // 64*65/2

typedef __attribute__((ext_vector_type(8))) short bf16x8;
typedef __attribute__((ext_vector_type(4))) float f32x4;

// ws layout (floats): [0]=nll_sum [1]=matdiff_sum [2]=sum_sq [3]=sxx [4]=syy
// [5]=smix(xy+yx) [6]=unused [7]=gram ticket counter ; [8..1032)=colsum[1024] ;
// [1032..9224)=sq[8192] ; byte 36896+ : bf16 total[8192*1024]
#define WS_TOT_BYTE_OFF 36896

#define FENCE() asm volatile("" ::: "memory")
#define BARRIER() do { FENCE(); __builtin_amdgcn_s_barrier(); FENCE(); } while (0)
#define MFMA16(d, x, y) d = __builtin_amdgcn_mfma_f32_16x16x32_bf16(x, y, d, 0, 0, 0)

__device__ __forceinline__ unsigned short f2bf(float f) {
  unsigned int u = __float_as_uint(f);
  u += 0x7fffu + ((u >> 16) & 1u);   // RNE
  return (unsigned short)(u >> 16);
}

__device__ __forceinline__ void async16(const void* g, void* l) {
  __builtin_amdgcn_global_load_lds(
      (const __attribute__((address_space(1))) unsigned int*)g,
      (__attribute__((address_space(3))) unsigned int*)l, 16, 0, 0);
}

__device__ __forceinline__ float wave_sum(float v) {
  v += __shfl_xor(v, 32);
  v += __shfl_xor(v, 16);
  v += __shfl_xor(v, 8);
  v += __shfl_xor(v, 4);
  v += __shfl_xor(v, 2);
  v += __shfl_xor(v, 1);
  return v;
}

__global__ void init_k(float* W) {
  int t = blockIdx.x * blockDim.x + threadIdx.x;
  if (t < 1032) W[t] = 0.f;   // scalars + ticket + colsum
}

// ---------------- fused pre: prep (256 blocks) + nll (16) + matdiff (1024) ---

__device__ void prep_body(int blk, const float* __restrict__ dense,
                          const float* __restrict__ sparse,
                          float* __restrict__ W,
                          unsigned short* __restrict__ tot) {
  float* colsum = W + 8;
  float* sq = W + 1032;
  const int t = threadIdx.x;
  const int lane = t & 63, wave = t >> 6;
  __shared__ float colsum_l[1024];
  #pragma unroll
  for (int x = 0; x < 4; ++x) colsum_l[t * 4 + x] = 0.f;

  float c[4][4];
  #pragma unroll
  for (int j = 0; j < 4; ++j)
    #pragma unroll
    for (int x = 0; x < 4; ++x) c[j][x] = 0.f;

  float rowtot = 0.f;
  const int rbase = blk * 32 + wave;   // 8 rows per wave, stride 4
  for (int i = 0; i < 8; ++i) {
    const int r = rbase + i * 4;
    const float* src = (r < B_ROWS) ? dense + (size_t)r * DIM
                                    : sparse + (size_t)(r - B_ROWS) * DIM;
    float sp = 0.f;
    #pragma unroll
    for (int j = 0; j < 4; ++j) {
      float4 v = ((const float4*)src)[lane + 64 * j];
      c[j][0] += v.x; c[j][1] += v.y; c[j][2] += v.z; c[j][3] += v.w;
      sp += v.x * v.x + v.y * v.y + v.z * v.z + v.w * v.w;
      ushort4 o;
      o.x = f2bf(v.x); o.y = f2bf(v.y); o.z = f2bf(v.z); o.w = f2bf(v.w);
      *(ushort4*)(tot + (size_t)r * DIM + (lane + 64 * j) * 4) = o;
    }
    sp = wave_sum(sp);
    if (lane == 0) { sq[r] = sp; rowtot += sp; }
  }
  if (lane == 0) atomicAdd(&W[2], rowtot);

  __syncthreads();
  #pragma unroll
  for (int j = 0; j < 4; ++j)
    #pragma unroll
    for (int x = 0; x < 4; ++x)
      atomicAdd(&colsum_l[4 * lane + 256 * j + x], c[j][x]);
  __syncthreads();
  #pragma unroll
  for (int x = 0; x < 4; ++x)
    atomicAdd(&colsum[t * 4 + x], colsum_l[t * 4 + x]);
}

__device__ void nll_body(int blk, const float* __restrict__ pred,
                         const int* __restrict__ tgt, float* __restrict__ W) {
  const int i = blk * 256 + threadIdx.x;
  float v = pred[(size_t)i * NCLS + tgt[i]];
  v = wave_sum(v);
  __shared__ float red[4];
  if ((threadIdx.x & 63) == 0) red[threadIdx.x >> 6] = v;
  __syncthreads();
  if (threadIdx.x == 0) atomicAdd(&W[0], red[0] + red[1] + red[2] + red[3]);
}

__device__ void matdiff_body(int blk, const float* __restrict__ trans,
                             float* __restrict__ W) {
  const int t = threadIdx.x;
  const int lane = t & 63, wave = t >> 6;
  const int b = blk * 4 + wave;
  const float* Tb = trans + (size_t)b * 4096;
  const int fr = lane & 15;
  const int k8 = (lane >> 4) * 8;
  bf16x8 frag[4][2];
  #pragma unroll
  for (int m = 0; m < 4; ++m) {
    #pragma unroll
    for (int kk = 0; kk < 2; ++kk) {
      const float* p = Tb + (size_t)(16 * m + fr) * 64 + kk * 32 + k8;
      float4 u0 = *(const float4*)p;
      float4 u1 = *(const float4*)(p + 4);
      bf16x8 f;
      f[0] = (short)f2bf(u0.x); f[1] = (short)f2bf(u0.y);
      f[2] = (short)f2bf(u0.z); f[3] = (short)f2bf(u0.w);
      f[4] = (short)f2bf(u1.x); f[5] = (short)f2bf(u1.y);
      f[6] = (short)f2bf(u1.z); f[7] = (short)f2bf(u1.w);
      frag[m][kk] = f;
    }
  }
  f32x4 acc[4][4];
  #pragma unroll
  for (int m = 0; m < 4; ++m)
    #pragma unroll
    for (int n = 0; n < 4; ++n) acc[m][n] = (f32x4)(0.f);
  #pragma unroll
  for (int kk = 0; kk < 2; ++kk)
    #pragma unroll
    for (int m = 0; m < 4; ++m)
      #pragma unroll
      for (int n = 0; n < 4; ++n)
        acc[m][n] = __builtin_amdgcn_mfma_f32_16x16x32_bf16(frag[m][kk], frag[n][kk],
                                                            acc[m][n], 0, 0, 0);
  float s = 0.f;
  const int crow = (lane >> 4) * 4;
  #pragma unroll
  for (int m = 0; m < 4; ++m)
    #pragma unroll
    for (int n = 0; n < 4; ++n)
      #pragma unroll
      for (int r = 0; r < 4; ++r) {
        int grow = 16 * m + crow + r;
        int gcol = 16 * n + fr;
        float g = acc[m][n][r];
        float d = (grow == gcol) ? (1.f - g) : (-g);
        s += d * d;
      }
  s = wave_sum(s);
  if (lane == 0) atomicAdd(&W[1], sqrtf(s));
}

__global__ __launch_bounds__(256) void fused_pre_k(
    const float* __restrict__ pred, const int* __restrict__ tgt,
    const float* __restrict__ trans, const float* __restrict__ dense,
    const float* __restrict__ sparse, float* __restrict__ W,
    unsigned short* __restrict__ tot) {
  const int blk = blockIdx.x;
  if (blk < 256)       prep_body(blk, dense, sparse, W, tot);
  else if (blk < 272)  nll_body(blk - 256, pred, tgt, W);
  else                 matdiff_body(blk - 272, trans, W);
}

// ---------------- gram: 128x128 tiles, 4 waves (2Mx2N), BK=32 phases ----------
// 3 blocks/CU (49KB LDS, <=170 VGPR): co-resident blocks hide barrier/latency
// stalls (m97/m114 mechanism).  Ring-3 plane-pairs (A,B planes of 8KB =
// [128r x 32c]); per phase: 8 ds_read_b128 + stage pair(kt+2) (4 gll, ~2-phase
// cover) + 16 MFMA (setprio) + counted vmcnt(4) + barrier.  NO explicit
// lgkmcnt/sched_barrier: compiler emits fine-grained waits, interleaving MFMA
// with LDS returns.  Swizzle (64B rows): slot' = slot ^ ((row>>1)&3), inverse
// applied at global source (rule #21); verified 0 conflicts in r3.
__global__ __launch_bounds__(256, 3) void gram_k(const unsigned short* __restrict__ tot,
                                                 float* __restrict__ W,
                                                 float* __restrict__ out) {
  __shared__ short As[3][4096];   // 3 ring slots x [128 rows x 32 cols]
  __shared__ short Bs[3][4096];
  __shared__ float sqA[128], sqB[128], red[4];
  const float* sq = W + 1032;
  const float* colsum = W + 8;
  const int t = threadIdx.x;              // 0..255
  const int lane = t & 63, wave = t >> 6; // 4 waves
  const int wr = wave >> 1, wc = wave & 1;

  // T1: XCD-contiguous remap; 2080 = 8*260 -> chunking bijective
  int p = (blockIdx.x & 7) * (NBLKG / 8) + (blockIdx.x >> 3);

  // decode linear id -> (bi, bj), bi <= bj, T=64
  int bi = (int)((2 * TILESG + 1 -
                  sqrtf((float)((2 * TILESG + 1) * (2 * TILESG + 1) - 8 * p))) * 0.5f);
  if (bi < 0) bi = 0;
  if (bi >= TILESG) bi = TILESG - 1;
  int start = bi * (2 * TILESG - bi + 1) / 2;
  while (p < start) { --bi; start = bi * (2 * TILESG - bi + 1) / 2; }
  while (p >= start + (TILESG - bi)) { start += TILESG - bi; ++bi; }
  const int bj = bi + (p - start);

  // staging: chunk c in {t, 256+t}; row = c>>2 ; slot = c&3 ;
  // global seg = slot ^ ((row>>1)&3) ; LDS dest linear = c*16B
  const int r0 = t >> 2;
  const int sg = (t & 3) ^ ((r0 >> 1) & 3);   // same for both chunks (row1=row0+64)
  const unsigned short* pA0 = tot + (size_t)(bi * 128 + r0) * DIM + sg * 8;
  const unsigned short* pA1 = pA0 + (size_t)64 * DIM;
  const unsigned short* pB0 = tot + (size_t)(bj * 128 + r0) * DIM + sg * 8;
  const unsigned short* pB1 = pB0 + (size_t)64 * DIM;
  const int ldo0 = t * 8, ldo1 = t * 8 + 2048;

  auto stage = [&](int kt, short* as_, short* bs_) {
    const size_t ko = (size_t)kt * 32;
    async16(pA0 + ko, as_ + ldo0);
    async16(pA1 + ko, as_ + ldo1);
    async16(pB0 + ko, bs_ + ldo0);
    async16(pB1 + ko, bs_ + ldo1);
  };

  short *a0 = &As[0][0], *a1 = &As[1][0], *a2 = &As[2][0];
  short *b0 = &Bs[0][0], *b1 = &Bs[1][0], *b2 = &Bs[2][0];

  // prologue: stage K-pairs 0 and 1 (8 loads in flight)
  stage(0, a0, b0);
  stage(1, a1, b1);

  // overlap with load latency: sq staging + per-block bandwidth coefficient
  if (t < 128) sqA[t] = sq[bi * 128 + t];
  else         sqB[t - 128] = sq[bj * 128 + (t - 128)];
  float csp = 0.f;
  #pragma unroll
  for (int j = 0; j < 16; ++j) { float v = colsum[lane + 64 * j]; csp += v * v; }
  csp = wave_sum(csp);
  double sumdots = (double)csp;
  double sum_sq = (double)W[2];
  double sumL2 = 2.0 * (double)NTOT * sum_sq - 2.0 * sumdots;
  double bwv = sumL2 / ((double)NTOT * (double)NTOT - (double)NTOT);
  const float cexp16 = (float)(4.0 / bwv) * 0.0625f;  // c/16: widest kernel coeff

  f32x4 acc[4][4];
  #pragma unroll
  for (int m = 0; m < 4; ++m)
    #pragma unroll
    for (int n = 0; n < 4; ++n) acc[m][n] = (f32x4)(0.f);

  // ds_read addressing: row*64B + ((q ^ ((fr>>1)&3))<<4)
  const int q = lane >> 4;
  const int fr = lane & 15;
  const int rb = (q ^ ((fr >> 1) & 3)) << 4;
  const int aoff = (wr * 64 + fr) * 64 + rb;   // + m*1024 per m-frag
  const int boff = (wc * 64 + fr) * 64 + rb;   // + n*1024 per n-frag

  // pair 0 landed (pair 1 may stay in flight; prologue reg-loads already
  // drained it anyway — counted schedule self-corrects from kt=1)
  asm volatile("s_waitcnt vmcnt(4)" ::: "memory");
  BARRIER();

  for (int kt = 0; kt < 32; ++kt) {
    bf16x8 a[4], b[4];
    #pragma unroll
    for (int m = 0; m < 4; ++m) a[m] = *(const bf16x8*)((const char*)a0 + aoff + m * 1024);
    #pragma unroll
    for (int n = 0; n < 4; ++n) b[n] = *(const bf16x8*)((const char*)b0 + boff + n * 1024);
    if (kt < 30) stage(kt + 2, a2, b2);
    __builtin_amdgcn_s_setprio(1);
    #pragma unroll
    for (int m = 0; m < 4; ++m)
      #pragma unroll
      for (int n = 0; n < 4; ++n) MFMA16(acc[m][n], a[m], b[n]);
    __builtin_amdgcn_s_setprio(0);
    if (kt < 30)       { asm volatile("s_waitcnt vmcnt(4)" ::: "memory"); }
    else if (kt == 30) { asm volatile("s_waitcnt vmcnt(0)" ::: "memory"); }
    if (kt < 31) BARRIER();
    short* ta = a0; a0 = a1; a1 = a2; a2 = ta;
    short* tb = b0; b0 = b1; b1 = b2; b2 = tb;
  }

  // epilogue: l2 -> 5-kernel sum. k_i = exp(-l2*c/2^i); exp of smallest,
  // then 4 squarings
  float s = 0.f;
  const int crow = (lane >> 4) * 4;
  #pragma unroll
  for (int m = 0; m < 4; ++m) {
    #pragma unroll
    for (int n = 0; n < 4; ++n) {
      #pragma unroll
      for (int r = 0; r < 4; ++r) {
        int il = wr * 64 + 16 * m + crow + r;
        int jl = wc * 64 + 16 * n + fr;
        float l2 = sqA[il] + sqB[jl] - 2.f * acc[m][n][r];
        l2 = fmaxf(l2, 0.f);
        float k4 = __expf(-l2 * cexp16);
        float k3 = k4 * k4;
        float k2 = k3 * k3;
        float k1 = k2 * k2;
        float k0 = k1 * k1;
        s += k0 + k1 + k2 + k3 + k4;
      }
    }
  }
  s = wave_sum(s);
  if (lane == 0) red[wave] = s;
  __syncthreads();
  if (t == 0) {
    float ts = red[0] + red[1] + red[2] + red[3];
    int idx; float wgt;
    if (bi == bj)      { idx = (bi < 32) ? 3 : 4; wgt = 1.f; }
    else if (bj < 32)  { idx = 3; wgt = 2.f; }
    else if (bi >= 32) { idx = 4; wgt = 2.f; }
    else               { idx = 5; wgt = 2.f; }
    atomicAdd(&W[idx], wgt * ts);
    __threadfence();
    unsigned int tk = atomicAdd((unsigned int*)(W + 7), 1u);
    if (tk == NBLKG - 1) {   // last block: final combine
      __threadfence();
      float nll = -*(volatile float*)(W + 0) / (float)B_ROWS;
      float mat =  *(volatile float*)(W + 1) / (float)B_ROWS;
      float sxx =  *(volatile float*)(W + 3);
      float syy =  *(volatile float*)(W + 4);
      float smx =  *(volatile float*)(W + 5);
      float mmd = (sxx + syy - smx) / ((float)B_ROWS * (float)B_ROWS);
      out[0] = 0.1f * nll + 0.001f * mat + 0.5f * mmd;
    }
  }
}

extern "C" void kernel_launch(void* const* d_in, const int* in_sizes, int n_in,
                              void* d_out, int out_size, void* d_ws, size_t ws_size,
                              hipStream_t stream) {
  const float* pred   = (const float*)d_in[0];
  const int*   tgt    = (const int*)d_in[1];
  const float* trans  = (const float*)d_in[2];
  const float* dense  = (const float*)d_in[3];
  const float* sparse = (const float*)d_in[4];
  float* W = (float*)d_ws;
  unsigned short* tot = (unsigned short*)((char*)d_ws + WS_TOT_BYTE_OFF);
  float* out = (float*)d_out;

  init_k<<<dim3(5), dim3(256), 0, stream>>>(W);
  fused_pre_k<<<dim3(1296), dim3(256), 0, stream>>>(pred, tgt, trans, dense, sparse, W, tot);
  gram_k<<<dim3(NBLKG), dim3(256), 0, stream>>>(tot, W, out);
}

// Round 5
// 226.426 us; speedup vs baseline: 1.5635x; 1.5635x over previous
//
#include <hip/hip_runtime.h>
#include <math.h>

#define B_ROWS 4096
#define DIM    1024
#define NTOT   8192
#define NCLS   40
#define TILES2 32   // 8192 / 256
#define NBLK   528  // 32*33/2

typedef __attribute__((ext_vector_type(8))) short bf16x8;
typedef __attribute__((ext_vector_type(4))) float f32x4;

// ws layout (floats): [0]=nll_sum [1]=matdiff_sum [2]=sum_sq [3]=sxx [4]=syy
// [5]=smix(xy+yx) [6]=unused [7]=gram ticket counter ; [8..1032)=colsum[1024] ;
// [1032..9224)=sq[8192] ; byte 36896+ : bf16 total[8192*1024]
#define WS_TOT_BYTE_OFF 36896

#define MFMA16(d, x, y) d = __builtin_amdgcn_mfma_f32_16x16x32_bf16(x, y, d, 0, 0, 0)

__device__ __forceinline__ unsigned short f2bf(float f) {
  unsigned int u = __float_as_uint(f);
  u += 0x7fffu + ((u >> 16) & 1u);   // RNE
  return (unsigned short)(u >> 16);
}

__device__ __forceinline__ void async16(const void* g, void* l) {
  __builtin_amdgcn_global_load_lds(
      (const __attribute__((address_space(1))) unsigned int*)g,
      (__attribute__((address_space(3))) unsigned int*)l, 16, 0, 0);
}

__device__ __forceinline__ float wave_sum(float v) {
  v += __shfl_xor(v, 32);
  v += __shfl_xor(v, 16);
  v += __shfl_xor(v, 8);
  v += __shfl_xor(v, 4);
  v += __shfl_xor(v, 2);
  v += __shfl_xor(v, 1);
  return v;
}

__global__ void init_k(float* W) {
  int t = blockIdx.x * blockDim.x + threadIdx.x;
  if (t < 1032) W[t] = 0.f;   // scalars + ticket + colsum
}

// ---------------- fused pre: prep (256 blocks) + nll (16) + matdiff (1024) ---

__device__ void prep_body(int blk, const float* __restrict__ dense,
                          const float* __restrict__ sparse,
                          float* __restrict__ W,
                          unsigned short* __restrict__ tot) {
  float* colsum = W + 8;
  float* sq = W + 1032;
  const int t = threadIdx.x;
  const int lane = t & 63, wave = t >> 6;
  __shared__ float colsum_l[1024];
  #pragma unroll
  for (int x = 0; x < 4; ++x) colsum_l[t * 4 + x] = 0.f;

  float c[4][4];
  #pragma unroll
  for (int j = 0; j < 4; ++j)
    #pragma unroll
    for (int x = 0; x < 4; ++x) c[j][x] = 0.f;

  float rowtot = 0.f;
  const int rbase = blk * 32 + wave;   // 8 rows per wave, stride 4
  for (int i = 0; i < 8; ++i) {
    const int r = rbase + i * 4;
    const float* src = (r < B_ROWS) ? dense + (size_t)r * DIM
                                    : sparse + (size_t)(r - B_ROWS) * DIM;
    float sp = 0.f;
    #pragma unroll
    for (int j = 0; j < 4; ++j) {
      float4 v = ((const float4*)src)[lane + 64 * j];
      c[j][0] += v.x; c[j][1] += v.y; c[j][2] += v.z; c[j][3] += v.w;
      sp += v.x * v.x + v.y * v.y + v.z * v.z + v.w * v.w;
      ushort4 o;
      o.x = f2bf(v.x); o.y = f2bf(v.y); o.z = f2bf(v.z); o.w = f2bf(v.w);
      *(ushort4*)(tot + (size_t)r * DIM + (lane + 64 * j) * 4) = o;
    }
    sp = wave_sum(sp);
    if (lane == 0) { sq[r] = sp; rowtot += sp; }
  }
  if (lane == 0) atomicAdd(&W[2], rowtot);

  __syncthreads();
  #pragma unroll
  for (int j = 0; j < 4; ++j)
    #pragma unroll
    for (int x = 0; x < 4; ++x)
      atomicAdd(&colsum_l[4 * lane + 256 * j + x], c[j][x]);
  __syncthreads();
  #pragma unroll
  for (int x = 0; x < 4; ++x)
    atomicAdd(&colsum[t * 4 + x], colsum_l[t * 4 + x]);
}

__device__ void nll_body(int blk, const float* __restrict__ pred,
                         const int* __restrict__ tgt, float* __restrict__ W) {
  const int i = blk * 256 + threadIdx.x;
  float v = pred[(size_t)i * NCLS + tgt[i]];
  v = wave_sum(v);
  __shared__ float red[4];
  if ((threadIdx.x & 63) == 0) red[threadIdx.x >> 6] = v;
  __syncthreads();
  if (threadIdx.x == 0) atomicAdd(&W[0], red[0] + red[1] + red[2] + red[3]);
}

__device__ void matdiff_body(int blk, const float* __restrict__ trans,
                             float* __restrict__ W) {
  const int t = threadIdx.x;
  const int lane = t & 63, wave = t >> 6;
  const int b = blk * 4 + wave;
  const float* Tb = trans + (size_t)b * 4096;
  const int fr = lane & 15;
  const int k8 = (lane >> 4) * 8;
  bf16x8 frag[4][2];
  #pragma unroll
  for (int m = 0; m < 4; ++m) {
    #pragma unroll
    for (int kk = 0; kk < 2; ++kk) {
      const float* p = Tb + (size_t)(16 * m + fr) * 64 + kk * 32 + k8;
      float4 u0 = *(const float4*)p;
      float4 u1 = *(const float4*)(p + 4);
      bf16x8 f;
      f[0] = (short)f2bf(u0.x); f[1] = (short)f2bf(u0.y);
      f[2] = (short)f2bf(u0.z); f[3] = (short)f2bf(u0.w);
      f[4] = (short)f2bf(u1.x); f[5] = (short)f2bf(u1.y);
      f[6] = (short)f2bf(u1.z); f[7] = (short)f2bf(u1.w);
      frag[m][kk] = f;
    }
  }
  f32x4 acc[4][4];
  #pragma unroll
  for (int m = 0; m < 4; ++m)
    #pragma unroll
    for (int n = 0; n < 4; ++n) acc[m][n] = (f32x4)(0.f);
  #pragma unroll
  for (int kk = 0; kk < 2; ++kk)
    #pragma unroll
    for (int m = 0; m < 4; ++m)
      #pragma unroll
      for (int n = 0; n < 4; ++n)
        acc[m][n] = __builtin_amdgcn_mfma_f32_16x16x32_bf16(frag[m][kk], frag[n][kk],
                                                            acc[m][n], 0, 0, 0);
  float s = 0.f;
  const int crow = (lane >> 4) * 4;
  #pragma unroll
  for (int m = 0; m < 4; ++m)
    #pragma unroll
    for (int n = 0; n < 4; ++n)
      #pragma unroll
      for (int r = 0; r < 4; ++r) {
        int grow = 16 * m + crow + r;
        int gcol = 16 * n + fr;
        float g = acc[m][n][r];
        float d = (grow == gcol) ? (1.f - g) : (-g);
        s += d * d;
      }
  s = wave_sum(s);
  if (lane == 0) atomicAdd(&W[1], sqrtf(s));
}

__global__ __launch_bounds__(256) void fused_pre_k(
    const float* __restrict__ pred, const int* __restrict__ tgt,
    const float* __restrict__ trans, const float* __restrict__ dense,
    const float* __restrict__ sparse, float* __restrict__ W,
    unsigned short* __restrict__ tot) {
  const int blk = blockIdx.x;
  if (blk < 256)       prep_body(blk, dense, sparse, W, tot);
  else if (blk < 272)  nll_body(blk - 256, pred, tgt, W);
  else                 matdiff_body(blk - 272, trans, W);
}

// ---------------- gram: 256x256 tiles, 8 waves (2Mx4N), BK=32, ring-4 --------
// Deep-covered counted pipeline (T3+T4): during tile kt stage tile kt+3
// (A-half ph0, B-half ph1, 2 loads/thread each); ONE vmcnt(8) per tile
// retires exactly tile kt+1 (12 loads steady in-flight, never drained to 0
// until the tail) -> every tile has ~6 phases of latency cover.  Per phase:
// ds_reads ; stage ; s_barrier ; lgkmcnt(0) (no sched_barrier — compiler dep
// waits guarantee correctness) ; setprio(1) 16xMFMA setprio(0) ; s_barrier.
// Slots statically indexed via 4x unroll (rule #20).  Swizzle for 64B rows:
// slot' = slot ^ ((row>>1)&3), inverse at global source (rule #21, r4-verified
// 0 conflicts / absmax 0).
__global__ __launch_bounds__(512, 2) void gram_k(const unsigned short* __restrict__ tot,
                                                 float* __restrict__ W,
                                                 float* __restrict__ out) {
  __shared__ short As[4][8192];   // [slot][256 rows x 32 k] = 16KB per slot
  __shared__ short Bs[4][8192];
  __shared__ float sqA[256], sqB[256], red[8];
  const float* sq = W + 1032;
  const float* colsum = W + 8;
  const int t = threadIdx.x;              // 0..511
  const int lane = t & 63, wave = t >> 6; // 8 waves
  const int wr = wave >> 2, wc = wave & 3;

  // T1: XCD-contiguous remap; 528 = 8*66 -> chunking bijective
  int p = (blockIdx.x & 7) * (NBLK / 8) + (blockIdx.x >> 3);

  // decode linear id -> (bi, bj), bi <= bj, T=32
  int bi = (int)((2 * TILES2 + 1 -
                  sqrtf((float)((2 * TILES2 + 1) * (2 * TILES2 + 1) - 8 * p))) * 0.5f);
  if (bi < 0) bi = 0;
  if (bi >= TILES2) bi = TILES2 - 1;
  int start = bi * (2 * TILES2 - bi + 1) / 2;
  while (p < start) { --bi; start = bi * (2 * TILES2 - bi + 1) / 2; }
  while (p >= start + (TILES2 - bi)) { start += TILES2 - bi; ++bi; }
  const int bj = bi + (p - start);

  // staging: chunks c0 = t (rows 0-127), c1 = 512+t (rows 128-255);
  // row = c>>2, slot_l = c&3, global seg = slot_l ^ ((row>>1)&3)
  // (identical for both chunks since 128/2 = 64 = 0 mod 4)
  const int r0 = t >> 2;
  const int sg = (t & 3) ^ ((r0 >> 1) & 3);
  const unsigned short* gA0 = tot + (size_t)(bi * 256 + r0) * DIM + sg * 8;
  const unsigned short* gA1 = gA0 + (size_t)128 * DIM;
  const unsigned short* gB0 = tot + (size_t)(bj * 256 + r0) * DIM + sg * 8;
  const unsigned short* gB1 = gB0 + (size_t)128 * DIM;
  const int ldo0 = t * 8, ldo1 = t * 8 + 4096;   // shorts within slot

  auto stageA = [&](int kt, short* sl) {
    const size_t ko = (size_t)kt * 32;
    async16(gA0 + ko, sl + ldo0);
    async16(gA1 + ko, sl + ldo1);
  };
  auto stageB = [&](int kt, short* sl) {
    const size_t ko = (size_t)kt * 32;
    async16(gB0 + ko, sl + ldo0);
    async16(gB1 + ko, sl + ldo1);
  };

  // prologue: stage tiles 0,1,2 (12 loads in flight)
  stageA(0, &As[0][0]); stageB(0, &Bs[0][0]);
  stageA(1, &As[1][0]); stageB(1, &Bs[1][0]);
  stageA(2, &As[2][0]); stageB(2, &Bs[2][0]);

  // overlap with load latency: sq staging + per-block bandwidth coefficient
  if (t < 256) sqA[t] = sq[bi * 256 + t];
  else         sqB[t - 256] = sq[bj * 256 + (t - 256)];
  float csp = 0.f;
  #pragma unroll
  for (int j = 0; j < 16; ++j) { float v = colsum[lane + 64 * j]; csp += v * v; }
  csp = wave_sum(csp);
  double sumdots = (double)csp;
  double sum_sq = (double)W[2];
  double sumL2 = 2.0 * (double)NTOT * sum_sq - 2.0 * sumdots;
  double bwv = sumL2 / ((double)NTOT * (double)NTOT - (double)NTOT);
  const float cexp16 = (float)(4.0 / bwv) * 0.0625f;  // c/16: widest kernel coeff

  f32x4 acc[8][4];
  #pragma unroll
  for (int m = 0; m < 8; ++m)
    #pragma unroll
    for (int n = 0; n < 4; ++n) acc[m][n] = (f32x4)(0.f);

  // ds_read addressing: row*64B + ((q ^ ((fr>>1)&3))<<4); all fragment rows
  // have (row>>1)&3 == (fr>>1)&3 (offsets are multiples of 8 rows)
  const int q = lane >> 4;
  const int fr = lane & 15;
  const int rb = (q ^ ((fr >> 1) & 3)) << 4;
  const int aoff = (wr * 128 + fr) * 64 + rb;   // + m*1024 per m-frag
  const int boff = (wc * 64 + fr) * 64 + rb;    // + n*1024 per n-frag

  // tile 0 landed (tiles 1,2 = newest 8 loads stay in flight)
  asm volatile("s_waitcnt vmcnt(8)" ::: "memory");
  __builtin_amdgcn_s_barrier();

  for (int u = 0; u < 8; ++u) {
    #pragma unroll
    for (int j = 0; j < 4; ++j) {
      const int kt = u * 4 + j;
      const char* cA = (const char*)&As[j][0];
      const char* cB = (const char*)&Bs[j][0];
      short* stA = &As[(j + 3) & 3][0];
      short* stB = &Bs[(j + 3) & 3][0];
      const bool st = (kt < 29);

      bf16x8 a[4], b[4];

      // ---- ph0: m0-3 x n0-3 ----
      #pragma unroll
      for (int m = 0; m < 4; ++m) a[m] = *(const bf16x8*)(cA + aoff + m * 1024);
      #pragma unroll
      for (int n = 0; n < 4; ++n) b[n] = *(const bf16x8*)(cB + boff + n * 1024);
      if (st) stageA(kt + 3, stA);
      __builtin_amdgcn_s_barrier();
      asm volatile("s_waitcnt lgkmcnt(0)" ::: "memory");
      __builtin_amdgcn_s_setprio(1);
      #pragma unroll
      for (int m = 0; m < 4; ++m)
        #pragma unroll
        for (int n = 0; n < 4; ++n) MFMA16(acc[m][n], a[m], b[n]);
      __builtin_amdgcn_s_setprio(0);
      __builtin_amdgcn_s_barrier();

      // ---- ph1: m4-7 x n0-3 (b[] reused from regs) ----
      #pragma unroll
      for (int m = 0; m < 4; ++m) a[m] = *(const bf16x8*)(cA + aoff + (4 + m) * 1024);
      if (st) stageB(kt + 3, stB);
      __builtin_amdgcn_s_barrier();
      asm volatile("s_waitcnt lgkmcnt(0)" ::: "memory");
      __builtin_amdgcn_s_setprio(1);
      #pragma unroll
      for (int m = 0; m < 4; ++m)
        #pragma unroll
        for (int n = 0; n < 4; ++n) MFMA16(acc[4 + m][n], a[m], b[n]);
      __builtin_amdgcn_s_setprio(0);
      // retire exactly tile kt+1 before next ph0 reads it
      if (kt < 29)       { asm volatile("s_waitcnt vmcnt(8)" ::: "memory"); }
      else if (kt == 29) { asm volatile("s_waitcnt vmcnt(4)" ::: "memory"); }
      else if (kt == 30) { asm volatile("s_waitcnt vmcnt(0)" ::: "memory"); }
      __builtin_amdgcn_s_barrier();
    }
  }

  // epilogue: l2 -> 5-kernel sum. k_i = exp(-l2*c/2^i); exp of smallest,
  // then 4 squarings
  float s = 0.f;
  const int crow = (lane >> 4) * 4;
  #pragma unroll
  for (int m = 0; m < 8; ++m) {
    #pragma unroll
    for (int n = 0; n < 4; ++n) {
      #pragma unroll
      for (int r = 0; r < 4; ++r) {
        int il = wr * 128 + 16 * m + crow + r;
        int jl = wc * 64 + 16 * n + fr;
        float l2 = sqA[il] + sqB[jl] - 2.f * acc[m][n][r];
        l2 = fmaxf(l2, 0.f);
        float k4 = __expf(-l2 * cexp16);
        float k3 = k4 * k4;
        float k2 = k3 * k3;
        float k1 = k2 * k2;
        float k0 = k1 * k1;
        s += k0 + k1 + k2 + k3 + k4;
      }
    }
  }
  s = wave_sum(s);
  if (lane == 0) red[wave] = s;
  __syncthreads();
  if (t == 0) {
    float ts = 0.f;
    #pragma unroll
    for (int w = 0; w < 8; ++w) ts += red[w];
    int idx; float wgt;
    if (bi == bj)      { idx = (bi < 16) ? 3 : 4; wgt = 1.f; }
    else if (bj < 16)  { idx = 3; wgt = 2.f; }
    else if (bi >= 16) { idx = 4; wgt = 2.f; }
    else               { idx = 5; wgt = 2.f; }
    atomicAdd(&W[idx], wgt * ts);
    __threadfence();
    unsigned int tk = atomicAdd((unsigned int*)(W + 7), 1u);
    if (tk == NBLK - 1) {   // last block: final combine
      __threadfence();
      float nll = -*(volatile float*)(W + 0) / (float)B_ROWS;
      float mat =  *(volatile float*)(W + 1) / (float)B_ROWS;
      float sxx =  *(volatile float*)(W + 3);
      float syy =  *(volatile float*)(W + 4);
      float smx =  *(volatile float*)(W + 5);
      float mmd = (sxx + syy - smx) / ((float)B_ROWS * (float)B_ROWS);
      out[0] = 0.1f * nll + 0.001f * mat + 0.5f * mmd;
    }
  }
}

extern "C" void kernel_launch(void* const* d_in, const int* in_sizes, int n_in,
                              void* d_out, int out_size, void* d_ws, size_t ws_size,
                              hipStream_t stream) {
  const float* pred   = (const float*)d_in[0];
  const int*   tgt    = (const int*)d_in[1];
  const float* trans  = (const float*)d_in[2];
  const float* dense  = (const float*)d_in[3];
  const float* sparse = (const float*)d_in[4];
  float* W = (float*)d_ws;
  unsigned short* tot = (unsigned short*)((char*)d_ws + WS_TOT_BYTE_OFF);
  float* out = (float*)d_out;

  init_k<<<dim3(5), dim3(256), 0, stream>>>(W);
  fused_pre_k<<<dim3(1296), dim3(256), 0, stream>>>(pred, tgt, trans, dense, sparse, W, tot);
  gram_k<<<dim3(NBLK), dim3(512), 0, stream>>>(tot, W, out);
}